// Round 9
// baseline (7566.457 us; speedup 1.0000x reference)
//
#include <hip/hip_runtime.h>

typedef float f4 __attribute__((ext_vector_type(4)));
typedef _Float16 h8v __attribute__((ext_vector_type(8)));
typedef _Float16 h2 __attribute__((ext_vector_type(2)));
typedef __fp16 fp16v2 __attribute__((ext_vector_type(2)));
typedef float f32x4 __attribute__((ext_vector_type(4)));

static constexpr int NB = 128, NT = 4096, NI = 64, NH = 256, NO = 64;
static constexpr int CPB = 32;           // chains per block: 2 groups x 16
static constexpr int NBLK = NB / CPB;    // 4 blocks
static constexpr size_t XP_BYTES = (size_t)NB * NT * NH * 2;

union I4H8 { int4 i; h8v h; };
union H2I2 { int i; _Float16 h[2]; };
union PKU  { fp16v2 v; int i; };

__device__ __forceinline__ int pk2(float a, float b) {
#if __has_builtin(__builtin_amdgcn_cvt_pkrtz)
    PKU u; u.v = __builtin_amdgcn_cvt_pkrtz(a, b); return u.i;
#else
    H2I2 u; u.h[0] = (_Float16)a; u.h[1] = (_Float16)b; return u.i;
#endif
}
__device__ __forceinline__ h8v pack8(f4 lo, f4 hi) {
    h8v r;
    r[0] = (_Float16)lo.x; r[1] = (_Float16)lo.y; r[2] = (_Float16)lo.z; r[3] = (_Float16)lo.w;
    r[4] = (_Float16)hi.x; r[5] = (_Float16)hi.y; r[6] = (_Float16)hi.z; r[7] = (_Float16)hi.w;
    return r;
}
__device__ __forceinline__ f32x4 mfma16(h8v a, h8v b, f32x4 c) {
    return __builtin_amdgcn_mfma_f32_16x16x32_f16(a, b, c, 0, 0, 0);
}
__device__ __forceinline__ float fast_tanh(float x) {
    float e = __builtin_amdgcn_exp2f(x * 2.885390081777927f); // 2*log2(e)
    return 1.0f - 2.0f * __builtin_amdgcn_rcpf(e + 1.0f);
}
__device__ __forceinline__ float fdot2(h2 a, h2 b, float c) {
#if __has_builtin(__builtin_amdgcn_fdot2)
    return __builtin_amdgcn_fdot2(a, b, c, false);
#else
    return c + (float)a[0] * (float)b[0] + (float)a[1] * (float)b[1];
#endif
}
__device__ __forceinline__ h2 toh2(int v) { union { int i; h2 h; } u; u.i = v; return u.h; }

__device__ __forceinline__ void lds_barrier() {
    asm volatile("s_waitcnt lgkmcnt(0)\n\ts_barrier" ::: "memory");
}
__device__ __forceinline__ void unp4(int2 v, float o[4]) {
    H2I2 u0, u1; u0.i = v.x; u1.i = v.y;
    o[0] = (float)u0.h[0]; o[1] = (float)u0.h[1];
    o[2] = (float)u1.h[0]; o[3] = (float)u1.h[1];
}

// ======================= pass 1: xp = x @ Wih^T + b_ih + b_hh (fp16) =======================
__global__ __launch_bounds__(256, 1) void xp_pre(
    const float* __restrict__ x, const float* __restrict__ wih,
    const float* __restrict__ bih, const float* __restrict__ bhh,
    int* __restrict__ xpg)
{
    __shared__ int xs[64 * 32];
    __shared__ int os[64 * 128];

    const int tid = threadIdx.x;
    const int w = tid >> 6, l = tid & 63;
    const int b = blockIdx.x >> 1;
    const int t0 = (blockIdx.x & 1) * (NT / 2);

    h2 wr[4][32];
    float bs[4];
#pragma unroll
    for (int a = 0; a < 4; ++a) {
        const int j = 4 * l + a;
        const f4* src = (const f4*)(wih + (size_t)j * NI);
#pragma unroll
        for (int u = 0; u < 16; ++u) {
            f4 v = src[u];
            wr[a][2 * u]     = toh2(pk2(v.x, v.y));
            wr[a][2 * u + 1] = toh2(pk2(v.z, v.w));
        }
        bs[a] = bih[j] + bhh[j];
    }

    const float* xbase = x + ((size_t)b * NT + t0) * NI;
    const int NCH = (NT / 2) / 64;

    f4 ld[4];
#pragma unroll
    for (int k = 0; k < 4; ++k) ld[k] = ((const f4*)xbase)[tid * 4 + k];

    for (int ch = 0; ch < NCH; ++ch) {
        {
            int4 w0, w1;
            w0.x = pk2(ld[0].x, ld[0].y); w0.y = pk2(ld[0].z, ld[0].w);
            w0.z = pk2(ld[1].x, ld[1].y); w0.w = pk2(ld[1].z, ld[1].w);
            w1.x = pk2(ld[2].x, ld[2].y); w1.y = pk2(ld[2].z, ld[2].w);
            w1.z = pk2(ld[3].x, ld[3].y); w1.w = pk2(ld[3].z, ld[3].w);
            *(int4*)&xs[tid * 8] = w0;
            *(int4*)&xs[tid * 8 + 4] = w1;
        }
        __syncthreads();
        if (ch + 1 < NCH) {
            const f4* nx = (const f4*)(xbase + (size_t)(ch + 1) * 64 * NI);
#pragma unroll
            for (int k = 0; k < 4; ++k) ld[k] = nx[tid * 4 + k];
        }
#pragma unroll 1
        for (int tt = 0; tt < 16; ++tt) {
            const int tl = tt * 4 + w;
            const int4* xr = (const int4*)&xs[tl * 32];
            int4 xv[8];
#pragma unroll
            for (int u = 0; u < 8; ++u) xv[u] = xr[u];
            const int* xd = (const int*)xv;
            float acc[4] = {0.f, 0.f, 0.f, 0.f};
#pragma unroll
            for (int kk = 0; kk < 32; ++kk) {
                const h2 hv = toh2(xd[kk]);
#pragma unroll
                for (int a = 0; a < 4; ++a) acc[a] = fdot2(wr[a][kk], hv, acc[a]);
            }
            int2 pk;
            pk.x = pk2(acc[0] + bs[0], acc[1] + bs[1]);
            pk.y = pk2(acc[2] + bs[2], acc[3] + bs[3]);
            *(int2*)&os[tl * 128 + l * 2] = pk;
        }
        __syncthreads();
        {
            int4* dst = (int4*)xpg + (size_t)(b * NT + t0 + ch * 64) * 32;
            const int4* s4 = (const int4*)os;
#pragma unroll
            for (int k = 0; k < 8; ++k) dst[k * 256 + tid] = s4[k * 256 + tid];
        }
        __syncthreads();
    }
}

// ======================= pass 2: dual-group zero-shuffle recurrence =======================
// Maps HW-verified (R6-R8): A lane l: rows (l&15), k=32kt+4*(l>>4)+{0..3,16..19};
// B lane l: col l&15, same k; LDS slot = l (16B), 1KB per kt. D lane l: col l&15,
// row R=64w+16mt+4*(l>>4)+rg -> tanh(D) IS next-step B elem in the SAME lane.
template<int WV>
__device__ __forceinline__ void dual_body(
    int t,
    const char* __restrict__ xpA, const char* __restrict__ xpB,
    const char* rbA, const char* rbB, char* wbA, char* wbB,
    const h8v (&Ah)[4][8],
    I4H8& boA0, I4H8& boA1, I4H8& boB0, I4H8& boB1,
    f32x4 (&accA)[4], f32x4 (&accB)[4],
    int2 (&xqAr)[4], int2 (&xqBr)[4])
{
    // unpack xp: A uses xp(t), B uses xp(t-1)
    float xa[4][4], xb[4][4];
#pragma unroll
    for (int mt = 0; mt < 4; ++mt) { unp4(xqAr[mt], xa[mt]); unp4(xqBr[mt], xb[mt]); }
    // refill rings for t+2 / t+1 (depth-2: >1 full iteration in flight)
    const size_t tA = (size_t)((t + 2 < NT) ? t + 2 : NT - 1) * 512;
    const size_t tB = (size_t)((t + 1 < NT) ? t + 1 : NT - 1) * 512;
#pragma unroll
    for (int mt = 0; mt < 4; ++mt) {
        xqAr[mt] = *(const int2*)(xpA + tA + mt * 32);
        xqBr[mt] = *(const int2*)(xpB + tB + mt * 32);
    }

    // ---- phase 1: MFMA_A  ||  tanh_B -> publish h_B(t-1) ----
    int4 bf[8];
#pragma unroll
    for (int kt = 0; kt < 8; ++kt)
        if ((kt >> 1) != WV) bf[kt] = *(const int4*)(rbA + kt * 1024);
#pragma unroll
    for (int mt = 0; mt < 4; ++mt) accA[mt] = mfma16(Ah[mt][2 * WV], boA0.h, f32x4{0.f, 0.f, 0.f, 0.f});
#pragma unroll
    for (int mt = 0; mt < 4; ++mt) accA[mt] = mfma16(Ah[mt][2 * WV + 1], boA1.h, accA[mt]);
    // tanh_B: independent of accA -> scheduler fills MFMA issue gaps
    float thB[4][4];
#pragma unroll
    for (int mt = 0; mt < 4; ++mt)
#pragma unroll
        for (int rg = 0; rg < 4; ++rg) thB[mt][rg] = fast_tanh(accB[mt][rg] + xb[mt][rg]);
#pragma unroll
    for (int kt = 0; kt < 8; ++kt) {
        if ((kt >> 1) != WV) {
            I4H8 u; u.i = bf[kt];
#pragma unroll
            for (int mt = 0; mt < 4; ++mt) accA[mt] = mfma16(Ah[mt][kt], u.h, accA[mt]);
        }
    }
    boB0.i = int4{pk2(thB[0][0], thB[0][1]), pk2(thB[0][2], thB[0][3]),
                  pk2(thB[1][0], thB[1][1]), pk2(thB[1][2], thB[1][3])};
    boB1.i = int4{pk2(thB[2][0], thB[2][1]), pk2(thB[2][2], thB[2][3]),
                  pk2(thB[3][0], thB[3][1]), pk2(thB[3][2], thB[3][3])};
    *(int4*)wbB = boB0.i;
    *(int4*)(wbB + 1024) = boB1.i;
    lds_barrier();

    // ---- phase 2: MFMA_B  ||  tanh_A -> publish h_A(t) ----
    int4 bg[8];
#pragma unroll
    for (int kt = 0; kt < 8; ++kt)
        if ((kt >> 1) != WV) bg[kt] = *(const int4*)(rbB + kt * 1024);
#pragma unroll
    for (int mt = 0; mt < 4; ++mt) accB[mt] = mfma16(Ah[mt][2 * WV], boB0.h, f32x4{0.f, 0.f, 0.f, 0.f});
#pragma unroll
    for (int mt = 0; mt < 4; ++mt) accB[mt] = mfma16(Ah[mt][2 * WV + 1], boB1.h, accB[mt]);
    float thA[4][4];
#pragma unroll
    for (int mt = 0; mt < 4; ++mt)
#pragma unroll
        for (int rg = 0; rg < 4; ++rg) thA[mt][rg] = fast_tanh(accA[mt][rg] + xa[mt][rg]);
#pragma unroll
    for (int kt = 0; kt < 8; ++kt) {
        if ((kt >> 1) != WV) {
            I4H8 u; u.i = bg[kt];
#pragma unroll
            for (int mt = 0; mt < 4; ++mt) accB[mt] = mfma16(Ah[mt][kt], u.h, accB[mt]);
        }
    }
    boA0.i = int4{pk2(thA[0][0], thA[0][1]), pk2(thA[0][2], thA[0][3]),
                  pk2(thA[1][0], thA[1][1]), pk2(thA[1][2], thA[1][3])};
    boA1.i = int4{pk2(thA[2][0], thA[2][1]), pk2(thA[2][2], thA[2][3]),
                  pk2(thA[3][0], thA[3][1]), pk2(thA[3][2], thA[3][3])};
    *(int4*)wbA = boA0.i;
    *(int4*)(wbA + 1024) = boA1.i;
    lds_barrier();
}

template<int WV>
__device__ void dual_run(
    const char* __restrict__ xpg, const float* __restrict__ whh,
    char* bufAB, float* hf, int b0)
{
    const int l = threadIdx.x & 63;
    const int n = l & 15;
    const int g = l >> 4;

    // A-frags of Whh, shared by both chain groups (128 VGPR)
    h8v Ah[4][8];
#pragma unroll
    for (int mt = 0; mt < 4; ++mt) {
        const int row = 64 * WV + 16 * mt + n;
#pragma unroll
        for (int kt = 0; kt < 8; ++kt) {
            const f4* pr = (const f4*)(whh + (size_t)row * NH + kt * 32 + g * 4);
            Ah[mt][kt] = pack8(pr[0], pr[4]);
        }
    }

    const char* xpA = xpg + (size_t)(b0 + n) * NT * 512 + (size_t)(64 * WV + 4 * g) * 2;
    const char* xpB = xpg + (size_t)(b0 + 16 + n) * NT * 512 + (size_t)(64 * WV + 4 * g) * 2;

    const char* rbA = bufAB + l * 16;
    const char* rbB = bufAB + 8192 + l * 16;
    char* wbA = bufAB + (2 * WV) * 1024 + l * 16;
    char* wbB = bufAB + 8192 + (2 * WV) * 1024 + l * 16;

    I4H8 boA0, boA1, boB0, boB1;
    boB0.i = int4{0, 0, 0, 0}; boB1.i = int4{0, 0, 0, 0};
    f32x4 accA[4], accB[4];
#pragma unroll
    for (int mt = 0; mt < 4; ++mt) accB[mt] = f32x4{0.f, 0.f, 0.f, 0.f};

    __syncthreads();  // LDS zeroed by caller

    // ---- peel t=0: h_A(0) = tanh(xp_A(0)); h_B(-1) = 0 already in bufB/boB ----
    {
        float th[4][4];
#pragma unroll
        for (int mt = 0; mt < 4; ++mt) {
            int2 v = *(const int2*)(xpA + mt * 32);
            float xv[4]; unp4(v, xv);
#pragma unroll
            for (int rg = 0; rg < 4; ++rg) th[mt][rg] = fast_tanh(xv[rg]);
        }
        boA0.i = int4{pk2(th[0][0], th[0][1]), pk2(th[0][2], th[0][3]),
                      pk2(th[1][0], th[1][1]), pk2(th[1][2], th[1][3])};
        boA1.i = int4{pk2(th[2][0], th[2][1]), pk2(th[2][2], th[2][3]),
                      pk2(th[3][0], th[3][1]), pk2(th[3][2], th[3][3])};
        *(int4*)wbA = boA0.i;
        *(int4*)(wbA + 1024) = boA1.i;
    }
    lds_barrier();

    // prefetch rings (depth 2)
    int2 xqA0[4], xqA1[4], xqB0[4], xqB1[4];
#pragma unroll
    for (int mt = 0; mt < 4; ++mt) {
        xqA0[mt] = *(const int2*)(xpA + (size_t)1 * 512 + mt * 32);
        xqA1[mt] = *(const int2*)(xpA + (size_t)2 * 512 + mt * 32);
        xqB0[mt] = *(const int2*)(xpB + (size_t)0 * 512 + mt * 32);
        xqB1[mt] = *(const int2*)(xpB + (size_t)1 * 512 + mt * 32);
    }

#pragma unroll 1
    for (int t = 1; t <= NT - 3; t += 2) {
        dual_body<WV>(t,     xpA, xpB, rbA, rbB, wbA, wbB, Ah,
                      boA0, boA1, boB0, boB1, accA, accB, xqA0, xqB0);
        dual_body<WV>(t + 1, xpA, xpB, rbA, rbB, wbA, wbB, Ah,
                      boA0, boA1, boB0, boB1, accA, accB, xqA1, xqB1);
    }

    // ---- peel t = NT-1 (ring 0), no refills; write final h to hf ----
    {
        float xa[4][4], xb[4][4];
#pragma unroll
        for (int mt = 0; mt < 4; ++mt) { unp4(xqA0[mt], xa[mt]); unp4(xqB0[mt], xb[mt]); }
        // phase 1: MFMA_A || tanh_B -> h_B(NT-2)
        int4 bf[8];
#pragma unroll
        for (int kt = 0; kt < 8; ++kt)
            if ((kt >> 1) != WV) bf[kt] = *(const int4*)(rbA + kt * 1024);
#pragma unroll
        for (int mt = 0; mt < 4; ++mt) accA[mt] = mfma16(Ah[mt][2 * WV], boA0.h, f32x4{0.f, 0.f, 0.f, 0.f});
#pragma unroll
        for (int mt = 0; mt < 4; ++mt) accA[mt] = mfma16(Ah[mt][2 * WV + 1], boA1.h, accA[mt]);
        float thB[4][4];
#pragma unroll
        for (int mt = 0; mt < 4; ++mt)
#pragma unroll
            for (int rg = 0; rg < 4; ++rg) thB[mt][rg] = fast_tanh(accB[mt][rg] + xb[mt][rg]);
#pragma unroll
        for (int kt = 0; kt < 8; ++kt) {
            if ((kt >> 1) != WV) {
                I4H8 u; u.i = bf[kt];
#pragma unroll
                for (int mt = 0; mt < 4; ++mt) accA[mt] = mfma16(Ah[mt][kt], u.h, accA[mt]);
            }
        }
        boB0.i = int4{pk2(thB[0][0], thB[0][1]), pk2(thB[0][2], thB[0][3]),
                      pk2(thB[1][0], thB[1][1]), pk2(thB[1][2], thB[1][3])};
        boB1.i = int4{pk2(thB[2][0], thB[2][1]), pk2(thB[2][2], thB[2][3]),
                      pk2(thB[3][0], thB[3][1]), pk2(thB[3][2], thB[3][3])};
        *(int4*)wbB = boB0.i;
        *(int4*)(wbB + 1024) = boB1.i;
        lds_barrier();
        // phase 2: MFMA_B -> z_B(NT-1); tanh_A -> h_A(NT-1) -> hf
        int4 bg[8];
#pragma unroll
        for (int kt = 0; kt < 8; ++kt)
            if ((kt >> 1) != WV) bg[kt] = *(const int4*)(rbB + kt * 1024);
#pragma unroll
        for (int mt = 0; mt < 4; ++mt) accB[mt] = mfma16(Ah[mt][2 * WV], boB0.h, f32x4{0.f, 0.f, 0.f, 0.f});
#pragma unroll
        for (int mt = 0; mt < 4; ++mt) accB[mt] = mfma16(Ah[mt][2 * WV + 1], boB1.h, accB[mt]);
#pragma unroll
        for (int kt = 0; kt < 8; ++kt) {
            if ((kt >> 1) != WV) {
                I4H8 u; u.i = bg[kt];
#pragma unroll
                for (int mt = 0; mt < 4; ++mt) accB[mt] = mfma16(Ah[mt][kt], u.h, accB[mt]);
            }
        }
#pragma unroll
        for (int mt = 0; mt < 4; ++mt) {
            f4 hv;
            hv.x = fast_tanh(accA[mt][0] + xa[mt][0]);
            hv.y = fast_tanh(accA[mt][1] + xa[mt][1]);
            hv.z = fast_tanh(accA[mt][2] + xa[mt][2]);
            hv.w = fast_tanh(accA[mt][3] + xa[mt][3]);
            *(f4*)(hf + (size_t)n * NH + 64 * WV + 16 * mt + 4 * g) = hv;
        }
        // final tanh_B: h_B(NT-1) = tanh(z_B(NT-1) + xp_B(NT-1));  xp_B(NT-1) == xqB1
#pragma unroll
        for (int mt = 0; mt < 4; ++mt) {
            float xv[4]; unp4(xqB1[mt], xv);
            f4 hv;
            hv.x = fast_tanh(accB[mt][0] + xv[0]);
            hv.y = fast_tanh(accB[mt][1] + xv[1]);
            hv.z = fast_tanh(accB[mt][2] + xv[2]);
            hv.w = fast_tanh(accB[mt][3] + xv[3]);
            *(f4*)(hf + (size_t)(16 + n) * NH + 64 * WV + 16 * mt + 4 * g) = hv;
        }
    }
}

__global__ __launch_bounds__(256, 1) void rnn_dual(
    const char* __restrict__ xpg, const float* __restrict__ whh,
    const float* __restrict__ wy, const float* __restrict__ by,
    float* __restrict__ out)
{
    __shared__ int4 bufAB[2 * 8 * 64];   // bufA [0,8KB) + bufB [8KB,16KB)
    __shared__ float hf[CPB * NH];       // 32 KB

    const int tid = threadIdx.x;
    const int w = tid >> 6;
    const int b0 = blockIdx.x * CPB;

    {
        int4 z{0, 0, 0, 0};
        bufAB[tid] = z; bufAB[tid + 256] = z; bufAB[tid + 512] = z; bufAB[tid + 768] = z;
    }
    // (first __syncthreads is inside dual_run; barrier counts identical across waves)
    if (w == 0)      dual_run<0>(xpg, whh, (char*)bufAB, hf, b0);
    else if (w == 1) dual_run<1>(xpg, whh, (char*)bufAB, hf, b0);
    else if (w == 2) dual_run<2>(xpg, whh, (char*)bufAB, hf, b0);
    else             dual_run<3>(xpg, whh, (char*)bufAB, hf, b0);

    __syncthreads();

    // ---- epilogue: y = h_last @ Wy^T + by  (32 chains x 64 outputs) ----
    const int c = tid >> 3;          // chain 0..31
    const int o0 = (tid & 7) * 8;    // 8 outputs each
    const f4* hp = (const f4*)(hf + (size_t)c * NH);
#pragma unroll 2
    for (int k = 0; k < 8; ++k) {
        const int o = o0 + k;
        float acc = by[o];
        const f4* wr = (const f4*)(wy + (size_t)o * NH);
#pragma unroll 8
        for (int u = 0; u < NH / 4; ++u) {
            f4 wv = wr[u], hv = hp[u];
            acc += wv.x * hv.x + wv.y * hv.y + wv.z * hv.z + wv.w * hv.w;
        }
        out[(size_t)(b0 + c) * NO + o] = acc;
    }
}

// ======================= fallback (R2 kernel, used only if d_ws too small) =======================
__global__ __launch_bounds__(256, 1) void rnn_fb(
    const float* __restrict__ x, const float* __restrict__ wih,
    const float* __restrict__ whhg, const float* __restrict__ bih,
    const float* __restrict__ bhh, const float* __restrict__ wy,
    const float* __restrict__ by, float* __restrict__ out)
{
    typedef _Float16 h8t __attribute__((ext_vector_type(8)));
    __shared__ h2 hbuf[2][NH / 2];
    __shared__ h2 xbuf[2][16 * NI / 2];
    __shared__ float hfs[NH];

    const int j = threadIdx.x;
    const int b = blockIdx.x;

    h2 whr[NH / 2];
    {
        const f4* src = (const f4*)(whhg + (size_t)j * NH);
#pragma unroll
        for (int q = 0; q < NH / 4; ++q) {
            f4 v = src[q];
            whr[2 * q]     = toh2(pk2(v.x, v.y));
            whr[2 * q + 1] = toh2(pk2(v.z, v.w));
        }
    }
    h2 wir[NI / 2];
    {
        const f4* src = (const f4*)(wih + (size_t)j * NI);
#pragma unroll
        for (int q = 0; q < NI / 4; ++q) {
            f4 v = src[q];
            wir[2 * q]     = toh2(pk2(v.x, v.y));
            wir[2 * q + 1] = toh2(pk2(v.z, v.w));
        }
    }
    const float bias = bih[j] + bhh[j];
    const float* xb = x + (size_t)b * NT * NI;
    {
        f4 v = ((const f4*)xb)[j];
        xbuf[0][2 * j]     = toh2(pk2(v.x, v.y));
        xbuf[0][2 * j + 1] = toh2(pk2(v.z, v.w));
    }
    if (j < NH / 2) { h2 z; z[0] = (_Float16)0.f; z[1] = (_Float16)0.f; hbuf[0][j] = z; }
    __syncthreads();

    float hval = 0.f;
    f4 xnext;
    int p = 0;
#pragma unroll 1
    for (int t = 0; t < NT; ++t) {
        const int s = t & 15, c = t >> 4;
        if (s == 0 && t + 16 < NT) xnext = ((const f4*)(xb + (size_t)(t + 16) * NI))[j];
        float a0 = bias, a1 = 0.f, a2 = 0.f, a3 = 0.f;
        {
            const h8t* xp = (const h8t*)(&xbuf[c & 1][s * (NI / 2)]);
#pragma unroll
            for (int r = 0; r < NI / 8; ++r) {
                h8t v = xp[r];
                a0 = fdot2(__builtin_shufflevector(v, v, 0, 1), wir[4 * r + 0], a0);
                a1 = fdot2(__builtin_shufflevector(v, v, 2, 3), wir[4 * r + 1], a1);
                a2 = fdot2(__builtin_shufflevector(v, v, 4, 5), wir[4 * r + 2], a2);
                a3 = fdot2(__builtin_shufflevector(v, v, 6, 7), wir[4 * r + 3], a3);
            }
        }
        {
            const h8t* hp = (const h8t*)(&hbuf[p][0]);
#pragma unroll
            for (int r = 0; r < NH / 8; ++r) {
                h8t v = hp[r];
                a0 = fdot2(__builtin_shufflevector(v, v, 0, 1), whr[4 * r + 0], a0);
                a1 = fdot2(__builtin_shufflevector(v, v, 2, 3), whr[4 * r + 1], a1);
                a2 = fdot2(__builtin_shufflevector(v, v, 4, 5), whr[4 * r + 2], a2);
                a3 = fdot2(__builtin_shufflevector(v, v, 6, 7), whr[4 * r + 3], a3);
            }
        }
        hval = fast_tanh((a0 + a1) + (a2 + a3));
        ((_Float16*)hbuf[p ^ 1])[j] = (_Float16)hval;
        if (s == 15 && t + 1 < NT) {
            xbuf[(c + 1) & 1][2 * j]     = toh2(pk2(xnext.x, xnext.y));
            xbuf[(c + 1) & 1][2 * j + 1] = toh2(pk2(xnext.z, xnext.w));
        }
        __syncthreads();
        p ^= 1;
    }
    hfs[j] = hval;
    __syncthreads();
    if (j < NO) {
        float acc = by[j];
        const f4* wrow = (const f4*)(wy + (size_t)j * NH);
        const f4* hp = (const f4*)hfs;
#pragma unroll
        for (int q = 0; q < NH / 4; ++q) {
            f4 w = wrow[q]; f4 h = hp[q];
            acc += w.x * h.x + w.y * h.y + w.z * h.z + w.w * h.w;
        }
        out[b * NO + j] = acc;
    }
}

extern "C" void kernel_launch(void* const* d_in, const int* in_sizes, int n_in,
                              void* d_out, int out_size, void* d_ws, size_t ws_size,
                              hipStream_t stream) {
    const float* x   = (const float*)d_in[0];
    const float* wih = (const float*)d_in[1];
    const float* whh = (const float*)d_in[2];
    const float* bih = (const float*)d_in[3];
    const float* bhh = (const float*)d_in[4];
    const float* wy  = (const float*)d_in[5];
    const float* by  = (const float*)d_in[6];
    float* out = (float*)d_out;

    if (ws_size >= XP_BYTES) {
        xp_pre<<<dim3(256), dim3(256), 0, stream>>>(x, wih, bih, bhh, (int*)d_ws);
        rnn_dual<<<dim3(NBLK), dim3(256), 0, stream>>>((const char*)d_ws, whh, wy, by, out);
    } else {
        rnn_fb<<<dim3(NB), dim3(256), 0, stream>>>(x, wih, whh, bih, bhh, wy, by, out);
    }
}

// Round 10
// 2886.392 us; speedup vs baseline: 2.6214x; 2.6214x over previous
//
#include <hip/hip_runtime.h>

typedef float f4 __attribute__((ext_vector_type(4)));
typedef _Float16 h8v __attribute__((ext_vector_type(8)));
typedef _Float16 h2 __attribute__((ext_vector_type(2)));
typedef __fp16 fp16v2 __attribute__((ext_vector_type(2)));
typedef float f32x4 __attribute__((ext_vector_type(4)));

static constexpr int NB = 128, NT = 4096, NI = 64, NH = 256, NO = 64;
static constexpr int CPB = 16;           // chains per block
static constexpr int NBLK = NB / CPB;    // 8 blocks
static constexpr size_t XP_BYTES = (size_t)NB * NT * NH * 2;
#define SCF 2.885390081777927f           // 2*log2(e), folded into Whh and xp

union I4H8 { int4 i; h8v h; };
union H2I2 { int i; _Float16 h[2]; };
union PKU  { fp16v2 v; int i; };

__device__ __forceinline__ int pk2(float a, float b) {
#if __has_builtin(__builtin_amdgcn_cvt_pkrtz)
    PKU u; u.v = __builtin_amdgcn_cvt_pkrtz(a, b); return u.i;
#else
    H2I2 u; u.h[0] = (_Float16)a; u.h[1] = (_Float16)b; return u.i;
#endif
}
__device__ __forceinline__ h8v pack8(f4 lo, f4 hi) {
    h8v r;
    r[0] = (_Float16)lo.x; r[1] = (_Float16)lo.y; r[2] = (_Float16)lo.z; r[3] = (_Float16)lo.w;
    r[4] = (_Float16)hi.x; r[5] = (_Float16)hi.y; r[6] = (_Float16)hi.z; r[7] = (_Float16)hi.w;
    return r;
}
__device__ __forceinline__ f4 scl4(f4 v, float s) {
    f4 r; r.x = v.x * s; r.y = v.y * s; r.z = v.z * s; r.w = v.w * s; return r;
}
__device__ __forceinline__ f32x4 mfma16(h8v a, h8v b, f32x4 c) {
    return __builtin_amdgcn_mfma_f32_16x16x32_f16(a, b, c, 0, 0, 0);
}
__device__ __forceinline__ float fdot2(h2 a, h2 b, float c) {
#if __has_builtin(__builtin_amdgcn_fdot2)
    return __builtin_amdgcn_fdot2(a, b, c, false);
#else
    return c + (float)a[0] * (float)b[0] + (float)a[1] * (float)b[1];
#endif
}
__device__ __forceinline__ h2 toh2(int v) { union { int i; h2 h; } u; u.i = v; return u.h; }
__device__ __forceinline__ float fast_tanh(float x) {  // fallback path only (unscaled input)
    float e = __builtin_amdgcn_exp2f(x * SCF);
    return 1.0f - 2.0f * __builtin_amdgcn_rcpf(e + 1.0f);
}
// tanh from PRE-SCALED argument z = SCF*x
__device__ __forceinline__ float tanh_s(float z) {
    float e = __builtin_amdgcn_exp2f(z);
    return 1.0f - 2.0f * __builtin_amdgcn_rcpf(e + 1.0f);
}
__device__ __forceinline__ void lds_barrier() {
    asm volatile("s_waitcnt lgkmcnt(0)\n\ts_barrier" ::: "memory");
}

// ======================= pass 1: xp = SCF * (x @ Wih^T + b_ih + b_hh), fp16 =======================
__global__ __launch_bounds__(256, 1) void xp_pre(
    const float* __restrict__ x, const float* __restrict__ wih,
    const float* __restrict__ bih, const float* __restrict__ bhh,
    int* __restrict__ xpg)
{
    __shared__ int xs[64 * 32];
    __shared__ int os[64 * 128];

    const int tid = threadIdx.x;
    const int w = tid >> 6, l = tid & 63;
    const int b = blockIdx.x >> 1;
    const int t0 = (blockIdx.x & 1) * (NT / 2);

    h2 wr[4][32];
    float bs[4];
#pragma unroll
    for (int a = 0; a < 4; ++a) {
        const int j = 4 * l + a;
        const f4* src = (const f4*)(wih + (size_t)j * NI);
#pragma unroll
        for (int u = 0; u < 16; ++u) {
            f4 v = src[u];
            wr[a][2 * u]     = toh2(pk2(v.x, v.y));
            wr[a][2 * u + 1] = toh2(pk2(v.z, v.w));
        }
        bs[a] = (bih[j] + bhh[j]) * SCF;   // pre-scaled bias
    }

    const float* xbase = x + ((size_t)b * NT + t0) * NI;
    const int NCH = (NT / 2) / 64;

    f4 ld[4];
#pragma unroll
    for (int k = 0; k < 4; ++k) ld[k] = ((const f4*)xbase)[tid * 4 + k];

    for (int ch = 0; ch < NCH; ++ch) {
        {
            int4 w0, w1;
            w0.x = pk2(ld[0].x, ld[0].y); w0.y = pk2(ld[0].z, ld[0].w);
            w0.z = pk2(ld[1].x, ld[1].y); w0.w = pk2(ld[1].z, ld[1].w);
            w1.x = pk2(ld[2].x, ld[2].y); w1.y = pk2(ld[2].z, ld[2].w);
            w1.z = pk2(ld[3].x, ld[3].y); w1.w = pk2(ld[3].z, ld[3].w);
            *(int4*)&xs[tid * 8] = w0;
            *(int4*)&xs[tid * 8 + 4] = w1;
        }
        __syncthreads();
        if (ch + 1 < NCH) {
            const f4* nx = (const f4*)(xbase + (size_t)(ch + 1) * 64 * NI);
#pragma unroll
            for (int k = 0; k < 4; ++k) ld[k] = nx[tid * 4 + k];
        }
#pragma unroll 1
        for (int tt = 0; tt < 16; ++tt) {
            const int tl = tt * 4 + w;
            const int4* xr = (const int4*)&xs[tl * 32];
            int4 xv[8];
#pragma unroll
            for (int u = 0; u < 8; ++u) xv[u] = xr[u];
            const int* xd = (const int*)xv;
            float acc[4] = {0.f, 0.f, 0.f, 0.f};
#pragma unroll
            for (int kk = 0; kk < 32; ++kk) {
                const h2 hv = toh2(xd[kk]);
#pragma unroll
                for (int a = 0; a < 4; ++a) acc[a] = fdot2(wr[a][kk], hv, acc[a]);
            }
            int2 pk;
            pk.x = pk2(fmaf(acc[0], SCF, bs[0]), fmaf(acc[1], SCF, bs[1]));
            pk.y = pk2(fmaf(acc[2], SCF, bs[2]), fmaf(acc[3], SCF, bs[3]));
            *(int2*)&os[tl * 128 + l * 2] = pk;
        }
        __syncthreads();
        {
            int4* dst = (int4*)xpg + (size_t)(b * NT + t0 + ch * 64) * 32;
            const int4* s4 = (const int4*)os;
#pragma unroll
            for (int k = 0; k < 8; ++k) dst[k * 256 + tid] = s4[k * 256 + tid];
        }
        __syncthreads();
    }
}

// ======================= pass 2: 8-wave M-split zero-shuffle recurrence =======================
// Verified maps (R6-R9): A lane l: rows base+(l&15)? no - A lane l holds row (l&15) of its
// M-tile, k = 32kt+4*(l>>4)+{0..3,16..19}. B lane l: col l&15, same k; slot l (16B), 1KB/kt.
// D lane l: col l&15, row = tile_base + 4*(l>>4) + rg.
// Wave w owns rows [32w,32w+32) == K-tile w -> tanh(D) IS own-kt B-frag: i = rg + 4*mt.
template<int WV, int PB>
__device__ __forceinline__ void step8(
    const char* rb,                 // LDS base + l*16
    const h8v (&Ah)[2][8],
    I4H8& bo,                       // own kt=WV B-tile (register)
    int2 (&xq)[2],                  // xp ring slot for this parity
    const char* xaddr,              // refill source (t+2, clamped)
    bool lastStep, float* hf, int n, int g)
{
    // acc init directly from xp (pre-scaled; no bias add, no zero-init)
    f32x4 acc[2];
#pragma unroll
    for (int mt = 0; mt < 2; ++mt) {
        H2I2 u0, u1; u0.i = xq[mt].x; u1.i = xq[mt].y;
        acc[mt][0] = (float)u0.h[0]; acc[mt][1] = (float)u0.h[1];
        acc[mt][2] = (float)u1.h[0]; acc[mt][3] = (float)u1.h[1];
    }
    // refill ring (stays in flight across lds_barrier)
#pragma unroll
    for (int mt = 0; mt < 2; ++mt) xq[mt] = *(const int2*)(xaddr + mt * 32);

    // foreign-kt reads (7 x ds_read_b128)
    int4 bf[8];
#pragma unroll
    for (int kt = 0; kt < 8; ++kt)
        if (kt != WV) bf[kt] = *(const int4*)(rb + PB * 8192 + kt * 1024);

    // own-kt MFMAs first (register B), then foreign as reads land: 16 MFMA
    acc[0] = mfma16(Ah[0][WV], bo.h, acc[0]);
    acc[1] = mfma16(Ah[1][WV], bo.h, acc[1]);
#pragma unroll
    for (int kt = 0; kt < 8; ++kt) {
        if (kt != WV) {
            I4H8 u; u.i = bf[kt];
            acc[0] = mfma16(Ah[0][kt], u.h, acc[0]);
            acc[1] = mfma16(Ah[1][kt], u.h, acc[1]);
        }
    }

    // tanh (scale already folded into Whh and xp)
    float th[2][4];
#pragma unroll
    for (int mt = 0; mt < 2; ++mt)
#pragma unroll
        for (int rg = 0; rg < 4; ++rg) th[mt][rg] = tanh_s(acc[mt][rg]);

    // D->B register rename (same lane) + publish own tile
    bo.i = int4{pk2(th[0][0], th[0][1]), pk2(th[0][2], th[0][3]),
                pk2(th[1][0], th[1][1]), pk2(th[1][2], th[1][3])};
    *(int4*)((char*)rb + (PB ^ 1) * 8192 + WV * 1024) = bo.i;

    if (lastStep) {
#pragma unroll
        for (int mt = 0; mt < 2; ++mt) {
            f4 hv; hv.x = th[mt][0]; hv.y = th[mt][1]; hv.z = th[mt][2]; hv.w = th[mt][3];
            *(f4*)(hf + (size_t)n * NH + 32 * WV + 16 * mt + 4 * g) = hv;
        }
    }
    lds_barrier();
}

template<int WV>
__device__ void run8(
    const char* __restrict__ xpg, const float* __restrict__ whh,
    char* hbB, float* hf, int b0)
{
    const int l = threadIdx.x & 63;
    const int n = l & 15;
    const int g = l >> 4;

    // cold: Whh A-frags for rows 32WV+16mt+n, SCALE-FOLDED (64 VGPR)
    h8v Ah[2][8];
#pragma unroll
    for (int mt = 0; mt < 2; ++mt) {
        const int row = 32 * WV + 16 * mt + n;
#pragma unroll
        for (int kt = 0; kt < 8; ++kt) {
            const f4* pr = (const f4*)(whh + (size_t)row * NH + kt * 32 + g * 4);
            Ah[mt][kt] = pack8(scl4(pr[0], SCF), scl4(pr[4], SCF));
        }
    }

    // per-lane xp source: rows 32WV+16mt+4g+{0..3} of chain n
    const char* xpp = xpg + (size_t)(b0 + n) * NT * 512 + (size_t)(32 * WV + 4 * g) * 2;

    int2 xq0[2], xq1[2];
#pragma unroll
    for (int mt = 0; mt < 2; ++mt) {
        xq0[mt] = *(const int2*)(xpp + (size_t)0 * 512 + mt * 32);
        xq1[mt] = *(const int2*)(xpp + (size_t)1 * 512 + mt * 32);
    }

    I4H8 bo; bo.i = int4{0, 0, 0, 0};
    const char* rb = hbB + (size_t)(l * 16);

    __syncthreads();  // LDS h-buffers zeroed

#pragma unroll 1
    for (int t = 0; t < NT; t += 2) {
        const size_t tA = (size_t)((t + 2 < NT) ? t + 2 : NT - 1) * 512;
        step8<WV, 0>(rb, Ah, bo, xq0, xpp + tA, false, hf, n, g);
        const size_t tB = (size_t)((t + 3 < NT) ? t + 3 : NT - 1) * 512;
        step8<WV, 1>(rb, Ah, bo, xq1, xpp + tB, (t + 2 >= NT), hf, n, g);
    }
}

__global__ __launch_bounds__(512, 1) void rnn8(
    const char* __restrict__ xpg, const float* __restrict__ whh,
    const float* __restrict__ wy, const float* __restrict__ by,
    float* __restrict__ out)
{
    __shared__ int4 hb[2 * 8 * 64];    // 16 KB: [buf][kt][slot l]
    __shared__ float hf[CPB * NH];     // 16 KB

    const int tid = threadIdx.x;
    const int w = tid >> 6;
    const int b0 = blockIdx.x * CPB;

    {
        int4 z{0, 0, 0, 0};
        hb[tid] = z; hb[tid + 512] = z;
    }
    // barriers inside run8 executed uniformly by all 8 waves
    if (w == 0)      run8<0>(xpg, whh, (char*)hb, hf, b0);
    else if (w == 1) run8<1>(xpg, whh, (char*)hb, hf, b0);
    else if (w == 2) run8<2>(xpg, whh, (char*)hb, hf, b0);
    else if (w == 3) run8<3>(xpg, whh, (char*)hb, hf, b0);
    else if (w == 4) run8<4>(xpg, whh, (char*)hb, hf, b0);
    else if (w == 5) run8<5>(xpg, whh, (char*)hb, hf, b0);
    else if (w == 6) run8<6>(xpg, whh, (char*)hb, hf, b0);
    else             run8<7>(xpg, whh, (char*)hb, hf, b0);

    // hf fully written before the last barrier inside run8
    // ---- epilogue: y = h_last @ Wy^T + by (16 chains x 64 outputs, 2/thread) ----
    const int c = tid >> 5;          // chain 0..15
    const int r = tid & 31;
    const f4* hp = (const f4*)(hf + (size_t)c * NH);
#pragma unroll
    for (int k = 0; k < 2; ++k) {
        const int o = r + 32 * k;
        float acc = by[o];
        const f4* wr = (const f4*)(wy + (size_t)o * NH);
#pragma unroll 8
        for (int u = 0; u < NH / 4; ++u) {
            f4 wv = wr[u], hv = hp[u];
            acc += wv.x * hv.x + wv.y * hv.y + wv.z * hv.z + wv.w * hv.w;
        }
        out[(size_t)(b0 + c) * NO + o] = acc;
    }
}

// ======================= fallback (R2 kernel, used only if d_ws too small) =======================
__global__ __launch_bounds__(256, 1) void rnn_fb(
    const float* __restrict__ x, const float* __restrict__ wih,
    const float* __restrict__ whhg, const float* __restrict__ bih,
    const float* __restrict__ bhh, const float* __restrict__ wy,
    const float* __restrict__ by, float* __restrict__ out)
{
    typedef _Float16 h8t __attribute__((ext_vector_type(8)));
    __shared__ h2 hbuf[2][NH / 2];
    __shared__ h2 xbuf[2][16 * NI / 2];
    __shared__ float hfs[NH];

    const int j = threadIdx.x;
    const int b = blockIdx.x;

    h2 whr[NH / 2];
    {
        const f4* src = (const f4*)(whhg + (size_t)j * NH);
#pragma unroll
        for (int q = 0; q < NH / 4; ++q) {
            f4 v = src[q];
            whr[2 * q]     = toh2(pk2(v.x, v.y));
            whr[2 * q + 1] = toh2(pk2(v.z, v.w));
        }
    }
    h2 wir[NI / 2];
    {
        const f4* src = (const f4*)(wih + (size_t)j * NI);
#pragma unroll
        for (int q = 0; q < NI / 4; ++q) {
            f4 v = src[q];
            wir[2 * q]     = toh2(pk2(v.x, v.y));
            wir[2 * q + 1] = toh2(pk2(v.z, v.w));
        }
    }
    const float bias = bih[j] + bhh[j];
    const float* xb = x + (size_t)b * NT * NI;
    {
        f4 v = ((const f4*)xb)[j];
        xbuf[0][2 * j]     = toh2(pk2(v.x, v.y));
        xbuf[0][2 * j + 1] = toh2(pk2(v.z, v.w));
    }
    if (j < NH / 2) { h2 z; z[0] = (_Float16)0.f; z[1] = (_Float16)0.f; hbuf[0][j] = z; }
    __syncthreads();

    float hval = 0.f;
    f4 xnext;
    int p = 0;
#pragma unroll 1
    for (int t = 0; t < NT; ++t) {
        const int s = t & 15, c = t >> 4;
        if (s == 0 && t + 16 < NT) xnext = ((const f4*)(xb + (size_t)(t + 16) * NI))[j];
        float a0 = bias, a1 = 0.f, a2 = 0.f, a3 = 0.f;
        {
            const h8t* xp = (const h8t*)(&xbuf[c & 1][s * (NI / 2)]);
#pragma unroll
            for (int r = 0; r < NI / 8; ++r) {
                h8t v = xp[r];
                a0 = fdot2(__builtin_shufflevector(v, v, 0, 1), wir[4 * r + 0], a0);
                a1 = fdot2(__builtin_shufflevector(v, v, 2, 3), wir[4 * r + 1], a1);
                a2 = fdot2(__builtin_shufflevector(v, v, 4, 5), wir[4 * r + 2], a2);
                a3 = fdot2(__builtin_shufflevector(v, v, 6, 7), wir[4 * r + 3], a3);
            }
        }
        {
            const h8t* hp = (const h8t*)(&hbuf[p][0]);
#pragma unroll
            for (int r = 0; r < NH / 8; ++r) {
                h8t v = hp[r];
                a0 = fdot2(__builtin_shufflevector(v, v, 0, 1), whr[4 * r + 0], a0);
                a1 = fdot2(__builtin_shufflevector(v, v, 2, 3), whr[4 * r + 1], a1);
                a2 = fdot2(__builtin_shufflevector(v, v, 4, 5), whr[4 * r + 2], a2);
                a3 = fdot2(__builtin_shufflevector(v, v, 6, 7), whr[4 * r + 3], a3);
            }
        }
        hval = fast_tanh((a0 + a1) + (a2 + a3));
        ((_Float16*)hbuf[p ^ 1])[j] = (_Float16)hval;
        if (s == 15 && t + 1 < NT) {
            xbuf[(c + 1) & 1][2 * j]     = toh2(pk2(xnext.x, xnext.y));
            xbuf[(c + 1) & 1][2 * j + 1] = toh2(pk2(xnext.z, xnext.w));
        }
        __syncthreads();
        p ^= 1;
    }
    hfs[j] = hval;
    __syncthreads();
    if (j < NO) {
        float acc = by[j];
        const f4* wrow = (const f4*)(wy + (size_t)j * NH);
        const f4* hp = (const f4*)hfs;
#pragma unroll
        for (int q = 0; q < NH / 4; ++q) {
            f4 w = wrow[q]; f4 h = hp[q];
            acc += w.x * h.x + w.y * h.y + w.z * h.z + w.w * h.w;
        }
        out[b * NO + j] = acc;
    }
}

extern "C" void kernel_launch(void* const* d_in, const int* in_sizes, int n_in,
                              void* d_out, int out_size, void* d_ws, size_t ws_size,
                              hipStream_t stream) {
    const float* x   = (const float*)d_in[0];
    const float* wih = (const float*)d_in[1];
    const float* whh = (const float*)d_in[2];
    const float* bih = (const float*)d_in[3];
    const float* bhh = (const float*)d_in[4];
    const float* wy  = (const float*)d_in[5];
    const float* by  = (const float*)d_in[6];
    float* out = (float*)d_out;

    if (ws_size >= XP_BYTES) {
        xp_pre<<<dim3(256), dim3(256), 0, stream>>>(x, wih, bih, bhh, (int*)d_ws);
        rnn8<<<dim3(NBLK), dim3(512), 0, stream>>>((const char*)d_ws, whh, wy, by, out);
    } else {
        rnn_fb<<<dim3(NB), dim3(256), 0, stream>>>(x, wih, whh, bih, bhh, wy, by, out);
    }
}

// Round 11
// 2700.679 us; speedup vs baseline: 2.8017x; 1.0688x over previous
//
#include <hip/hip_runtime.h>

typedef float f4 __attribute__((ext_vector_type(4)));
typedef _Float16 h8v __attribute__((ext_vector_type(8)));
typedef _Float16 h2 __attribute__((ext_vector_type(2)));
typedef __fp16 fp16v2 __attribute__((ext_vector_type(2)));
typedef float f32x4 __attribute__((ext_vector_type(4)));

static constexpr int NB = 128, NT = 4096, NI = 64, NH = 256, NO = 64;
static constexpr int CPB = 16;           // chains per block
static constexpr int NBLK = NB / CPB;    // 8 blocks
static constexpr size_t XP_BYTES = (size_t)NB * NT * NH * 2;
#define SCF 2.885390081777927f           // 2*log2(e), folded into Whh and xp

union I4H8 { int4 i; h8v h; };
union H2I2 { int i; _Float16 h[2]; };
union PKU  { fp16v2 v; int i; };

__device__ __forceinline__ int pk2(float a, float b) {
#if __has_builtin(__builtin_amdgcn_cvt_pkrtz)
    PKU u; u.v = __builtin_amdgcn_cvt_pkrtz(a, b); return u.i;
#else
    H2I2 u; u.h[0] = (_Float16)a; u.h[1] = (_Float16)b; return u.i;
#endif
}
__device__ __forceinline__ h8v pack8(f4 lo, f4 hi) {
    h8v r;
    r[0] = (_Float16)lo.x; r[1] = (_Float16)lo.y; r[2] = (_Float16)lo.z; r[3] = (_Float16)lo.w;
    r[4] = (_Float16)hi.x; r[5] = (_Float16)hi.y; r[6] = (_Float16)hi.z; r[7] = (_Float16)hi.w;
    return r;
}
__device__ __forceinline__ f4 scl4(f4 v, float s) {
    f4 r; r.x = v.x * s; r.y = v.y * s; r.z = v.z * s; r.w = v.w * s; return r;
}
__device__ __forceinline__ f32x4 mfma16(h8v a, h8v b, f32x4 c) {
    return __builtin_amdgcn_mfma_f32_16x16x32_f16(a, b, c, 0, 0, 0);
}
__device__ __forceinline__ float fdot2(h2 a, h2 b, float c) {
#if __has_builtin(__builtin_amdgcn_fdot2)
    return __builtin_amdgcn_fdot2(a, b, c, false);
#else
    return c + (float)a[0] * (float)b[0] + (float)a[1] * (float)b[1];
#endif
}
__device__ __forceinline__ h2 toh2(int v) { union { int i; h2 h; } u; u.i = v; return u.h; }
__device__ __forceinline__ float fast_tanh(float x) {  // fallback path only
    float e = __builtin_amdgcn_exp2f(x * SCF);
    return 1.0f - 2.0f * __builtin_amdgcn_rcpf(e + 1.0f);
}
__device__ __forceinline__ float tanh_s(float z) {     // z = SCF*x pre-scaled
    float e = __builtin_amdgcn_exp2f(z);
    return 1.0f - 2.0f * __builtin_amdgcn_rcpf(e + 1.0f);
}
__device__ __forceinline__ void lds_barrier() {
    asm volatile("s_waitcnt lgkmcnt(0)\n\ts_barrier" ::: "memory");
}

// ======================= pass 1: xp = SCF * (x @ Wih^T + b_ih + b_hh), fp16 =======================
__global__ __launch_bounds__(256, 1) void xp_pre(
    const float* __restrict__ x, const float* __restrict__ wih,
    const float* __restrict__ bih, const float* __restrict__ bhh,
    int* __restrict__ xpg)
{
    __shared__ int xs[64 * 32];
    __shared__ int os[64 * 128];

    const int tid = threadIdx.x;
    const int w = tid >> 6, l = tid & 63;
    const int b = blockIdx.x >> 1;
    const int t0 = (blockIdx.x & 1) * (NT / 2);

    h2 wr[4][32];
    float bs[4];
#pragma unroll
    for (int a = 0; a < 4; ++a) {
        const int j = 4 * l + a;
        const f4* src = (const f4*)(wih + (size_t)j * NI);
#pragma unroll
        for (int u = 0; u < 16; ++u) {
            f4 v = src[u];
            wr[a][2 * u]     = toh2(pk2(v.x, v.y));
            wr[a][2 * u + 1] = toh2(pk2(v.z, v.w));
        }
        bs[a] = (bih[j] + bhh[j]) * SCF;
    }

    const float* xbase = x + ((size_t)b * NT + t0) * NI;
    const int NCH = (NT / 2) / 64;

    f4 ld[4];
#pragma unroll
    for (int k = 0; k < 4; ++k) ld[k] = ((const f4*)xbase)[tid * 4 + k];

    for (int ch = 0; ch < NCH; ++ch) {
        {
            int4 w0, w1;
            w0.x = pk2(ld[0].x, ld[0].y); w0.y = pk2(ld[0].z, ld[0].w);
            w0.z = pk2(ld[1].x, ld[1].y); w0.w = pk2(ld[1].z, ld[1].w);
            w1.x = pk2(ld[2].x, ld[2].y); w1.y = pk2(ld[2].z, ld[2].w);
            w1.z = pk2(ld[3].x, ld[3].y); w1.w = pk2(ld[3].z, ld[3].w);
            *(int4*)&xs[tid * 8] = w0;
            *(int4*)&xs[tid * 8 + 4] = w1;
        }
        __syncthreads();
        if (ch + 1 < NCH) {
            const f4* nx = (const f4*)(xbase + (size_t)(ch + 1) * 64 * NI);
#pragma unroll
            for (int k = 0; k < 4; ++k) ld[k] = nx[tid * 4 + k];
        }
#pragma unroll 1
        for (int tt = 0; tt < 16; ++tt) {
            const int tl = tt * 4 + w;
            const int4* xr = (const int4*)&xs[tl * 32];
            int4 xv[8];
#pragma unroll
            for (int u = 0; u < 8; ++u) xv[u] = xr[u];
            const int* xd = (const int*)xv;
            float acc[4] = {0.f, 0.f, 0.f, 0.f};
#pragma unroll
            for (int kk = 0; kk < 32; ++kk) {
                const h2 hv = toh2(xd[kk]);
#pragma unroll
                for (int a = 0; a < 4; ++a) acc[a] = fdot2(wr[a][kk], hv, acc[a]);
            }
            int2 pk;
            pk.x = pk2(fmaf(acc[0], SCF, bs[0]), fmaf(acc[1], SCF, bs[1]));
            pk.y = pk2(fmaf(acc[2], SCF, bs[2]), fmaf(acc[3], SCF, bs[3]));
            *(int2*)&os[tl * 128 + l * 2] = pk;
        }
        __syncthreads();
        {
            int4* dst = (int4*)xpg + (size_t)(b * NT + t0 + ch * 64) * 32;
            const int4* s4 = (const int4*)os;
#pragma unroll
            for (int k = 0; k < 8; ++k) dst[k * 256 + tid] = s4[k * 256 + tid];
        }
        __syncthreads();
    }
}

// ======================= pass 2: 8-wave M-split zero-shuffle recurrence =======================
// Verified maps (R6-R10): A lane l: row (l&15) of its M-tile, k=32kt+4*(l>>4)+{0..3,16..19}.
// B lane l: col l&15, same k; LDS slot = l (16B), 1KB per kt.
// D lane l: col l&15, row = tile_base + 4*(l>>4) + rg.
// Wave w owns rows [32w,32w+32) == K-tile w -> tanh(D) IS own-kt B-frag (i = rg + 4*mt).
template<int WV, int PB>
__device__ __forceinline__ void step8(
    const char* rb,                 // LDS base + l*16
    const h8v (&Ah)[2][8],
    I4H8& bo,                       // own kt=WV B-tile (register)
    int2 (&xq)[2],                  // xp ring slot for this parity
    const char* xaddr,              // refill source (t+2, clamped)
    bool lastStep, float* hf, int n, int g)
{
    // 0) foreign-kt reads FIRST: DS queue saturates immediately after barrier
    int4 bf[8];
#pragma unroll
    for (int kt = 0; kt < 8; ++kt)
        if (kt != WV) bf[kt] = *(const int4*)(rb + PB * 8192 + kt * 1024);

    // 1) unpack xp -> even-chain acc init (VALU, hides under DS)
    f32x4 acc[2], ac2[2];
#pragma unroll
    for (int mt = 0; mt < 2; ++mt) {
        H2I2 u0, u1; u0.i = xq[mt].x; u1.i = xq[mt].y;
        acc[mt][0] = (float)u0.h[0]; acc[mt][1] = (float)u0.h[1];
        acc[mt][2] = (float)u1.h[0]; acc[mt][3] = (float)u1.h[1];
    }
    // 2) refill ring (VMEM; stays in flight across lds_barrier)
#pragma unroll
    for (int mt = 0; mt < 2; ++mt) xq[mt] = *(const int2*)(xaddr + mt * 32);

    // 3) MFMAs: 4 independent chains (even kt -> acc, odd kt -> ac2), own tile first
    __builtin_amdgcn_s_setprio(1);
    {
        constexpr int OPP = WV ^ 1;  // same parity-partner: ensures each chain gets a reg start
        // own tile (register B operand): parity WV&1
        acc[0] = mfma16(Ah[0][WV], bo.h, acc[0]);
        acc[1] = mfma16(Ah[1][WV], bo.h, acc[1]);
        // first foreign tile of the OTHER parity starts the second chain pair (C=0)
        {
            I4H8 u; u.i = bf[OPP];
            ac2[0] = mfma16(Ah[0][OPP], u.h, f32x4{0.f, 0.f, 0.f, 0.f});
            ac2[1] = mfma16(Ah[1][OPP], u.h, f32x4{0.f, 0.f, 0.f, 0.f});
        }
#pragma unroll
        for (int kt = 0; kt < 8; ++kt) {
            if (kt == WV || kt == OPP) continue;
            I4H8 u; u.i = bf[kt];
            if ((kt & 1) == (WV & 1)) {
                acc[0] = mfma16(Ah[0][kt], u.h, acc[0]);
                acc[1] = mfma16(Ah[1][kt], u.h, acc[1]);
            } else {
                ac2[0] = mfma16(Ah[0][kt], u.h, ac2[0]);
                ac2[1] = mfma16(Ah[1][kt], u.h, ac2[1]);
            }
        }
    }
    __builtin_amdgcn_s_setprio(0);

    // 4) merge chains + tanh (scale folded into Whh and xp)
    float th[2][4];
#pragma unroll
    for (int mt = 0; mt < 2; ++mt) {
        f32x4 s = acc[mt] + ac2[mt];
#pragma unroll
        for (int rg = 0; rg < 4; ++rg) th[mt][rg] = tanh_s(s[rg]);
    }

    // 5) D->B register rename (same lane) + publish own tile
    bo.i = int4{pk2(th[0][0], th[0][1]), pk2(th[0][2], th[0][3]),
                pk2(th[1][0], th[1][1]), pk2(th[1][2], th[1][3])};
    *(int4*)((char*)rb + (PB ^ 1) * 8192 + WV * 1024) = bo.i;

    if (lastStep) {
#pragma unroll
        for (int mt = 0; mt < 2; ++mt) {
            f4 hv; hv.x = th[mt][0]; hv.y = th[mt][1]; hv.z = th[mt][2]; hv.w = th[mt][3];
            *(f4*)(hf + (size_t)n * NH + 32 * WV + 16 * mt + 4 * g) = hv;
        }
    }
    lds_barrier();
}

template<int WV>
__device__ void run8(
    const char* __restrict__ xpg, const float* __restrict__ whh,
    char* hbB, float* hf, int b0)
{
    const int l = threadIdx.x & 63;
    const int n = l & 15;
    const int g = l >> 4;

    // cold: Whh A-frags for rows 32WV+16mt+n, SCALE-FOLDED (64 VGPR)
    h8v Ah[2][8];
#pragma unroll
    for (int mt = 0; mt < 2; ++mt) {
        const int row = 32 * WV + 16 * mt + n;
#pragma unroll
        for (int kt = 0; kt < 8; ++kt) {
            const f4* pr = (const f4*)(whh + (size_t)row * NH + kt * 32 + g * 4);
            Ah[mt][kt] = pack8(scl4(pr[0], SCF), scl4(pr[4], SCF));
        }
    }

    // per-lane xp source: rows 32WV+16mt+4g+{0..3} of chain n
    const char* xpp = xpg + (size_t)(b0 + n) * NT * 512 + (size_t)(32 * WV + 4 * g) * 2;

    int2 xq0[2], xq1[2];
#pragma unroll
    for (int mt = 0; mt < 2; ++mt) {
        xq0[mt] = *(const int2*)(xpp + (size_t)0 * 512 + mt * 32);
        xq1[mt] = *(const int2*)(xpp + (size_t)1 * 512 + mt * 32);
    }

    I4H8 bo; bo.i = int4{0, 0, 0, 0};
    const char* rb = hbB + (size_t)(l * 16);

    __syncthreads();  // LDS h-buffers zeroed

#pragma unroll 1
    for (int t = 0; t < NT; t += 2) {
        const size_t tA = (size_t)((t + 2 < NT) ? t + 2 : NT - 1) * 512;
        step8<WV, 0>(rb, Ah, bo, xq0, xpp + tA, false, hf, n, g);
        const size_t tB = (size_t)((t + 3 < NT) ? t + 3 : NT - 1) * 512;
        step8<WV, 1>(rb, Ah, bo, xq1, xpp + tB, (t + 2 >= NT), hf, n, g);
    }
}

__global__ __launch_bounds__(512, 1) void rnn8(
    const char* __restrict__ xpg, const float* __restrict__ whh,
    const float* __restrict__ wy, const float* __restrict__ by,
    float* __restrict__ out)
{
    __shared__ int4 hb[2 * 8 * 64];    // 16 KB: [buf][kt][slot l]
    __shared__ float hf[CPB * NH];     // 16 KB

    const int tid = threadIdx.x;
    const int w = tid >> 6;
    const int b0 = blockIdx.x * CPB;

    {
        int4 z{0, 0, 0, 0};
        hb[tid] = z; hb[tid + 512] = z;
    }
    // barriers inside run8 executed uniformly by all 8 waves
    if (w == 0)      run8<0>(xpg, whh, (char*)hb, hf, b0);
    else if (w == 1) run8<1>(xpg, whh, (char*)hb, hf, b0);
    else if (w == 2) run8<2>(xpg, whh, (char*)hb, hf, b0);
    else if (w == 3) run8<3>(xpg, whh, (char*)hb, hf, b0);
    else if (w == 4) run8<4>(xpg, whh, (char*)hb, hf, b0);
    else if (w == 5) run8<5>(xpg, whh, (char*)hb, hf, b0);
    else if (w == 6) run8<6>(xpg, whh, (char*)hb, hf, b0);
    else             run8<7>(xpg, whh, (char*)hb, hf, b0);

    // ---- epilogue: y = h_last @ Wy^T + by (16 chains x 64 outputs, 2/thread) ----
    const int c = tid >> 5;          // chain 0..15
    const int r = tid & 31;
    const f4* hp = (const f4*)(hf + (size_t)c * NH);
#pragma unroll
    for (int k = 0; k < 2; ++k) {
        const int o = r + 32 * k;
        float acc = by[o];
        const f4* wr = (const f4*)(wy + (size_t)o * NH);
#pragma unroll 8
        for (int u = 0; u < NH / 4; ++u) {
            f4 wv = wr[u], hv = hp[u];
            acc += wv.x * hv.x + wv.y * hv.y + wv.z * hv.z + wv.w * hv.w;
        }
        out[(size_t)(b0 + c) * NO + o] = acc;
    }
}

// ======================= fallback (R2 kernel, used only if d_ws too small) =======================
__global__ __launch_bounds__(256, 1) void rnn_fb(
    const float* __restrict__ x, const float* __restrict__ wih,
    const float* __restrict__ whhg, const float* __restrict__ bih,
    const float* __restrict__ bhh, const float* __restrict__ wy,
    const float* __restrict__ by, float* __restrict__ out)
{
    typedef _Float16 h8t __attribute__((ext_vector_type(8)));
    __shared__ h2 hbuf[2][NH / 2];
    __shared__ h2 xbuf[2][16 * NI / 2];
    __shared__ float hfs[NH];

    const int j = threadIdx.x;
    const int b = blockIdx.x;

    h2 whr[NH / 2];
    {
        const f4* src = (const f4*)(whhg + (size_t)j * NH);
#pragma unroll
        for (int q = 0; q < NH / 4; ++q) {
            f4 v = src[q];
            whr[2 * q]     = toh2(pk2(v.x, v.y));
            whr[2 * q + 1] = toh2(pk2(v.z, v.w));
        }
    }
    h2 wir[NI / 2];
    {
        const f4* src = (const f4*)(wih + (size_t)j * NI);
#pragma unroll
        for (int q = 0; q < NI / 4; ++q) {
            f4 v = src[q];
            wir[2 * q]     = toh2(pk2(v.x, v.y));
            wir[2 * q + 1] = toh2(pk2(v.z, v.w));
        }
    }
    const float bias = bih[j] + bhh[j];
    const float* xb = x + (size_t)b * NT * NI;
    {
        f4 v = ((const f4*)xb)[j];
        xbuf[0][2 * j]     = toh2(pk2(v.x, v.y));
        xbuf[0][2 * j + 1] = toh2(pk2(v.z, v.w));
    }
    if (j < NH / 2) { h2 z; z[0] = (_Float16)0.f; z[1] = (_Float16)0.f; hbuf[0][j] = z; }
    __syncthreads();

    float hval = 0.f;
    f4 xnext;
    int p = 0;
#pragma unroll 1
    for (int t = 0; t < NT; ++t) {
        const int s = t & 15, c = t >> 4;
        if (s == 0 && t + 16 < NT) xnext = ((const f4*)(xb + (size_t)(t + 16) * NI))[j];
        float a0 = bias, a1 = 0.f, a2 = 0.f, a3 = 0.f;
        {
            const h8t* xp = (const h8t*)(&xbuf[c & 1][s * (NI / 2)]);
#pragma unroll
            for (int r = 0; r < NI / 8; ++r) {
                h8t v = xp[r];
                a0 = fdot2(__builtin_shufflevector(v, v, 0, 1), wir[4 * r + 0], a0);
                a1 = fdot2(__builtin_shufflevector(v, v, 2, 3), wir[4 * r + 1], a1);
                a2 = fdot2(__builtin_shufflevector(v, v, 4, 5), wir[4 * r + 2], a2);
                a3 = fdot2(__builtin_shufflevector(v, v, 6, 7), wir[4 * r + 3], a3);
            }
        }
        {
            const h8t* hp = (const h8t*)(&hbuf[p][0]);
#pragma unroll
            for (int r = 0; r < NH / 8; ++r) {
                h8t v = hp[r];
                a0 = fdot2(__builtin_shufflevector(v, v, 0, 1), whr[4 * r + 0], a0);
                a1 = fdot2(__builtin_shufflevector(v, v, 2, 3), whr[4 * r + 1], a1);
                a2 = fdot2(__builtin_shufflevector(v, v, 4, 5), whr[4 * r + 2], a2);
                a3 = fdot2(__builtin_shufflevector(v, v, 6, 7), whr[4 * r + 3], a3);
            }
        }
        hval = fast_tanh((a0 + a1) + (a2 + a3));
        ((_Float16*)hbuf[p ^ 1])[j] = (_Float16)hval;
        if (s == 15 && t + 1 < NT) {
            xbuf[(c + 1) & 1][2 * j]     = toh2(pk2(xnext.x, xnext.y));
            xbuf[(c + 1) & 1][2 * j + 1] = toh2(pk2(xnext.z, xnext.w));
        }
        __syncthreads();
        p ^= 1;
    }
    hfs[j] = hval;
    __syncthreads();
    if (j < NO) {
        float acc = by[j];
        const f4* wrow = (const f4*)(wy + (size_t)j * NH);
        const f4* hp = (const f4*)hfs;
#pragma unroll
        for (int q = 0; q < NH / 4; ++q) {
            f4 w = wrow[q]; f4 h = hp[q];
            acc += w.x * h.x + w.y * h.y + w.z * h.z + w.w * h.w;
        }
        out[b * NO + j] = acc;
    }
}

extern "C" void kernel_launch(void* const* d_in, const int* in_sizes, int n_in,
                              void* d_out, int out_size, void* d_ws, size_t ws_size,
                              hipStream_t stream) {
    const float* x   = (const float*)d_in[0];
    const float* wih = (const float*)d_in[1];
    const float* whh = (const float*)d_in[2];
    const float* bih = (const float*)d_in[3];
    const float* bhh = (const float*)d_in[4];
    const float* wy  = (const float*)d_in[5];
    const float* by  = (const float*)d_in[6];
    float* out = (float*)d_out;

    if (ws_size >= XP_BYTES) {
        xp_pre<<<dim3(256), dim3(256), 0, stream>>>(x, wih, bih, bhh, (int*)d_ws);
        rnn8<<<dim3(NBLK), dim3(512), 0, stream>>>((const char*)d_ws, whh, wy, by, out);
    } else {
        rnn_fb<<<dim3(NB), dim3(256), 0, stream>>>(x, wih, whh, bih, bhh, wy, by, out);
    }
}